// Round 6
// baseline (122.291 us; speedup 1.0000x reference)
//
#include <hip/hip_runtime.h>
#include <hip/hip_bf16.h>
#include <stdint.h>

typedef __attribute__((ext_vector_type(4))) float f32x4;
typedef __attribute__((ext_vector_type(8))) short bf16x8;

#define NCH  128
#define NREL 8

__device__ __forceinline__ unsigned short f2bf(float f) {
    unsigned u = __builtin_bit_cast(unsigned, f);
    u += 0x7fffu + ((u >> 16) & 1u);          // RNE to bf16
    return (unsigned short)(u >> 16);
}

// ---------------------------------------------------------------------------
// ATTRIBUTION ROUND: source is byte-identical to R2 (67.9 us, best measured);
// the ONLY change is k_main launched 3x (idempotent) so
//   dur = P + H + M_first + 2*M_warm,  with  P + H + M_first = 67.9.
// ---------------------------------------------------------------------------
__global__ __launch_bounds__(256)
void k_prep(const float* __restrict__ W, unsigned short* __restrict__ Wb,
            int* __restrict__ cn, const unsigned char* __restrict__ um_raw) {
    int o = blockIdx.x * 256 + threadIdx.x;
    if (o < NREL * NCH * NCH) {
        int kk = o & 31;
        int h  = (o >> 5) & (NCH - 1);
        int kt = o >> 12;
        int k  = kt * 32 + kk;
        Wb[o] = f2bf(W[k * NCH + h]);
    }
    if (blockIdx.x == 0) {
        __shared__ unsigned sA, sB;
        const int t = threadIdx.x;
        if (t == 0) { sA = 0; sB = 0; }
        __syncthreads();
        unsigned a = 0, b = 0;
        #pragma unroll 4
        for (int p = t; p < 1024; p += 256) {
            unsigned v = um_raw[p];
            if ((p & 3) != 0) a |= v;
            if ((p & 7) == 4) b |= v;
        }
        if (a) atomicOr(&sA, 1u);
        if (b) atomicOr(&sB, 1u);
        __syncthreads();
        if (t == 0) {
            cn[0] = 0;
            cn[1] = sA ? 1 : (sB ? 4 : 8);    // mask element stride in bytes
        }
    }
}

__device__ __forceinline__ bool mask_used(const unsigned char* um, int stride, int s) {
    if (stride == 1) return um[s] != 0;
    if (stride == 4) return ((const int*)um)[s] != 0;
    return ((const long long*)um)[s] != 0;
}

__global__ __launch_bounds__(256)
void k_hist(const float* __restrict__ hb, const int* __restrict__ hm,
            const int* __restrict__ hs, float* __restrict__ out,
            int* __restrict__ cn, int* __restrict__ glist, int num_node) {
    __shared__ int ncList[32];
    __shared__ int cList[32];
    __shared__ int nNC, nC, gbase;
    const int t = threadIdx.x;
    if (t == 0) { nNC = 0; nC = 0; }
    __syncthreads();
    const int n = blockIdx.x * 32 + t;
    if (t < 32 && n < num_node) {
        const bool cached = (hs[0] > 0) && (hm[n] != -1);
        if (cached) { int p = atomicAdd(&nC, 1);  cList[p]  = n; }
        else        { int p = atomicAdd(&nNC, 1); ncList[p] = n; }
    }
    __syncthreads();
    const int hw = t >> 5, l = t & 31;
    int   node[4];
    f32x4 v[4];
    #pragma unroll 4
    for (int j = 0; j < 4; ++j) {
        const int i = hw + j * 8;
        node[j] = (i < nC) ? cList[i] : -1;
        if (node[j] >= 0)
            v[j] = *(const f32x4*)(hb + (long)node[j] * NCH + l * 4);
    }
    #pragma unroll 4
    for (int j = 0; j < 4; ++j) {
        if (node[j] >= 0)
            *(f32x4*)(out + (long)node[j] * NCH + l * 4) = v[j];
    }
    if (t == 0) gbase = atomicAdd(&cn[0], nNC);
    __syncthreads();
    if (t < nNC) glist[gbase + t] = ncList[t];
}

__global__ __launch_bounds__(256, 4)
void k_main(const float* __restrict__ x, const unsigned short* __restrict__ Wb,
            const int* __restrict__ ptr, const int* __restrict__ idx,
            const int* __restrict__ et, const unsigned char* __restrict__ um,
            const int* __restrict__ cn, const int* __restrict__ glist,
            float* __restrict__ out) {
    __shared__ __align__(16) char As[16 * NREL * NCH * 2];   // 32 KB, XOR-swizzled
    __shared__ int   nid[16];
    __shared__ float invdeg[16];

    const int cnt  = cn[0];
    const int base = blockIdx.x * 16;
    if (base >= cnt) return;
    const int mstride = cn[1];
    const int t = threadIdx.x;
    if (t < 16) {
        const int e = base + t;
        nid[t]    = (e < cnt) ? glist[e] : -1;
        invdeg[t] = 0.0f;
    }
    __syncthreads();

    const int hw = t >> 5;          // half-wave id 0..7
    const int l  = t & 31;          // lane in half-wave; owns channels 4l..4l+3
    const int lbase = t & 32;       // wave-lane base of this half-wave

    for (int rep = 0; rep < 2; ++rep) {
        const int nd = hw + rep * 8;
        const int n  = nid[nd];
        float acc[NREL][4];
        #pragma unroll
        for (int r = 0; r < NREL; ++r)
            #pragma unroll
            for (int j = 0; j < 4; ++j) acc[r][j] = 0.0f;
        if (n >= 0) {
            const int p0 = ptr[n], p1 = ptr[n + 1];
            const int deg = p1 - p0;
            if (l == 0) invdeg[nd] = (deg > 0) ? 1.0f / (float)deg : 0.0f;
            int myS = 0, myR = NREL;
            if (l < 16 && (p0 + l) < p1) {
                const int e = p0 + l;
                myS = idx[e];
                const int tt = et[e];
                myR = (mask_used(um, mstride, myS) && tt >= 0 && tt < NREL) ? tt : NREL;
            }
            const int dcap = deg < 16 ? deg : 16;
            #pragma unroll 2
            for (int ch = 0; ch < 2; ++ch) {
                int   rr8[8], ss8[8];
                f32x4 xv[8];
                #pragma unroll 8
                for (int e = 0; e < 8; ++e) {
                    rr8[e] = __shfl(myR, lbase + ch * 8 + e, 64);
                    ss8[e] = __shfl(myS, lbase + ch * 8 + e, 64);
                    xv[e]  = *(const f32x4*)(x + (long)ss8[e] * NCH + l * 4);
                }
                #pragma unroll 8
                for (int e = 0; e < 8; ++e) {
                    const int r = rr8[e];
                    #pragma unroll
                    for (int q = 0; q < NREL; ++q) {
                        const float sel = (r == q) ? 1.0f : 0.0f;
                        acc[q][0] += sel * xv[e].x;
                        acc[q][1] += sel * xv[e].y;
                        acc[q][2] += sel * xv[e].z;
                        acc[q][3] += sel * xv[e].w;
                    }
                }
            }
            (void)dcap;
            for (int e = p0 + 16; e < p1; ++e) {   // general fallback (deg > 16)
                const int s = idx[e];
                const int tt = et[e];
                if (mask_used(um, mstride, s) && tt >= 0 && tt < NREL) {
                    const f32x4 w = *(const f32x4*)(x + (long)s * NCH + l * 4);
                    #pragma unroll
                    for (int q = 0; q < NREL; ++q) {
                        const float sel = (tt == q) ? 1.0f : 0.0f;
                        acc[q][0] += sel * w.x;
                        acc[q][1] += sel * w.y;
                        acc[q][2] += sel * w.z;
                        acc[q][3] += sel * w.w;
                    }
                }
            }
        }
        #pragma unroll
        for (int q = 0; q < NREL; ++q) {
            ushort4 pkv;
            pkv.x = f2bf(acc[q][0]); pkv.y = f2bf(acc[q][1]);
            pkv.z = f2bf(acc[q][2]); pkv.w = f2bf(acc[q][3]);
            const int eb   = (q * NCH + l * 4) * 2;
            const int addr = (nd * 2048 + eb) ^ ((nd & 7) << 4);
            *(ushort4*)(As + addr) = pkv;
        }
    }
    __syncthreads();

    const int wv   = t >> 6;
    const int lane = t & 63;
    const int row  = lane & 15;
    const int koff = (lane >> 4) * 8;
    const int col0 = wv * 32 + row;
    f32x4 c0 = {0.f, 0.f, 0.f, 0.f}, c1 = {0.f, 0.f, 0.f, 0.f};
    #pragma unroll 8
    for (int kt = 0; kt < 32; ++kt) {
        const int aaddr = (row * 2048 + (kt * 32 + koff) * 2) ^ ((row & 7) << 4);
        const bf16x8 a  = *(const bf16x8*)(As + aaddr);
        const bf16x8 b0 = *(const bf16x8*)(Wb + ((kt * NCH + col0) << 5) + koff);
        const bf16x8 b1 = *(const bf16x8*)(Wb + ((kt * NCH + col0 + 16) << 5) + koff);
        c0 = __builtin_amdgcn_mfma_f32_16x16x32_bf16(a, b0, c0, 0, 0, 0);
        c1 = __builtin_amdgcn_mfma_f32_16x16x32_bf16(a, b1, c1, 0, 0, 0);
    }
    const int r4 = (lane >> 4) * 4;
    #pragma unroll
    for (int j = 0; j < 4; ++j) {
        const int rr = r4 + j;
        const int n  = nid[rr];
        if (n >= 0) {
            const float sc = invdeg[rr];
            out[(long)n * NCH + col0]      = c0[j] * sc;
            out[(long)n * NCH + col0 + 16] = c1[j] * sc;
        }
    }
}

extern "C" void kernel_launch(void* const* d_in, const int* in_sizes, int n_in,
                              void* d_out, int out_size, void* d_ws, size_t ws_size,
                              hipStream_t stream) {
    const float*         x   = (const float*)d_in[0];
    const float*         W   = (const float*)d_in[1];
    const float*         hb  = (const float*)d_in[2];
    const int*           ptr = (const int*)d_in[3];
    const int*           idx = (const int*)d_in[4];
    const int*           et  = (const int*)d_in[5];
    const unsigned char* um  = (const unsigned char*)d_in[6];
    const int*           hm  = (const int*)d_in[7];
    const int*           hs  = (const int*)d_in[8];
    float* out = (float*)d_out;

    const int num_node = in_sizes[7];           // history_map length

    int* cn    = (int*)d_ws;
    int* glist = (int*)((char*)d_ws + 256);
    size_t wb_off = 256 + (((size_t)num_node * 4 + 255) / 256) * 256;
    unsigned short* Wb = (unsigned short*)((char*)d_ws + wb_off);

    k_prep<<<(NREL * NCH * NCH + 255) / 256, 256, 0, stream>>>(W, Wb, cn, um);
    k_hist<<<(num_node + 31) / 32, 256, 0, stream>>>(hb, hm, hs, out, cn, glist, num_node);
    // ATTRIBUTION: k_main is idempotent -> run 3x; extra runs add 2*M_warm.
    k_main<<<(num_node + 15) / 16, 256, 0, stream>>>(x, Wb, ptr, idx, et, um, cn, glist, out);
    k_main<<<(num_node + 15) / 16, 256, 0, stream>>>(x, Wb, ptr, idx, et, um, cn, glist, out);
    k_main<<<(num_node + 15) / 16, 256, 0, stream>>>(x, Wb, ptr, idx, et, um, cn, glist, out);
}

// Round 7
// 76.934 us; speedup vs baseline: 1.5896x; 1.5896x over previous
//
#include <hip/hip_runtime.h>
#include <hip/hip_bf16.h>
#include <stdint.h>

typedef __attribute__((ext_vector_type(2))) float f32x2;
typedef __attribute__((ext_vector_type(4))) float f32x4;
typedef __attribute__((ext_vector_type(8))) short bf16x8;

#define NCH  128
#define NREL 8

__device__ __forceinline__ unsigned short f2bf(float f) {
    unsigned u = __builtin_bit_cast(unsigned, f);
    u += 0x7fffu + ((u >> 16) & 1u);          // RNE to bf16
    return (unsigned short)(u >> 16);
}

__device__ __forceinline__ bool mask_used(const unsigned char* um, int stride, int s) {
    if (stride == 1) return um[s] != 0;
    if (stride == 4) return ((const int*)um)[s] != 0;
    return ((const long long*)um)[s] != 0;
}

// ---------------------------------------------------------------------------
// K1: W fp32 -> bf16 Wb, B-fragment layout Wb[((kt*128+col)<<5)+kk].
// Block 0: zero cn[0], detect used_mask element width -> cn[1].
// ---------------------------------------------------------------------------
__global__ __launch_bounds__(256)
void k_prep(const float* __restrict__ W, unsigned short* __restrict__ Wb,
            int* __restrict__ cn, const unsigned char* __restrict__ um_raw) {
    const int o = blockIdx.x * 256 + threadIdx.x;
    if (o < NREL * NCH * NCH) {
        const int kk  = o & 31;
        const int col = (o >> 5) & (NCH - 1);
        const int kt  = o >> 12;
        Wb[o] = f2bf(W[(kt * 32 + kk) * NCH + col]);
    }
    if (blockIdx.x == 0) {
        __shared__ unsigned sA, sB;
        const int t = threadIdx.x;
        if (t == 0) { sA = 0; sB = 0; }
        __syncthreads();
        unsigned a = 0, b = 0;
        #pragma unroll 4
        for (int p = t; p < 1024; p += 256) {
            const unsigned v = um_raw[p];
            if ((p & 3) != 0) a |= v;   // bool stored 1B -> data off 4-align
            if ((p & 7) == 4) b |= v;   // int32 -> data at 4 mod 8
        }
        if (a) atomicOr(&sA, 1u);
        if (b) atomicOr(&sB, 1u);
        __syncthreads();
        if (t == 0) { cn[0] = 0; cn[1] = sA ? 1 : (sB ? 4 : 8); }
    }
}

// ---------------------------------------------------------------------------
// K2: 32 nodes per block. Ballot-classify; copy cached history rows to out;
// append non-cached ids to glist AND precompute per-edge metadata
//   eMeta[slot*16+j] = (rel<<24)|src   (bit29 of word0: deg>16 overflow)
// and invdegG[slot]. This moves k_main's serial idx->et->mask chain into a
// kernel with massive TLP slack.
// ---------------------------------------------------------------------------
__global__ __launch_bounds__(256)
void k_hist(const float* __restrict__ hb, const int* __restrict__ hm,
            const int* __restrict__ hs, const int* __restrict__ ptr,
            const int* __restrict__ idx, const int* __restrict__ et,
            const unsigned char* __restrict__ um, float* __restrict__ out,
            int* __restrict__ cn, int* __restrict__ glist,
            float* __restrict__ invdegG, int* __restrict__ eMeta,
            int num_node) {
    __shared__ int cList[32], ncList[32];
    __shared__ int nCs, nNCs, gbase;
    const int t = threadIdx.x;
    if (t < 64) {                                  // wave 0 classifies
        const int n = blockIdx.x * 32 + t;
        const bool valid  = (t < 32) && (n < num_node);
        const bool cached = valid && (hs[0] > 0) && (hm[n] != -1);
        const bool nc     = valid && !cached;
        const unsigned long long mC  = __ballot(cached);
        const unsigned long long mNC = __ballot(nc);
        const unsigned long long below = (1ull << t) - 1;
        if (cached) cList[__popcll(mC & below)]   = n;
        if (nc)     ncList[__popcll(mNC & below)] = n;
        if (t == 0) { nCs = __popcll(mC); nNCs = __popcll(mNC); }
    }
    __syncthreads();
    const int myC = nCs, myNC = nNCs;
    const int hw = t >> 5, l = t & 31;
    // ---- cached-row copy: half-wave per row
    {
        int   node[4];
        f32x4 v[4];
        #pragma unroll 4
        for (int j = 0; j < 4; ++j) {
            const int i = hw + j * 8;
            node[j] = (i < myC) ? cList[i] : -1;
            if (node[j] >= 0)
                v[j] = *(const f32x4*)(hb + (long)node[j] * NCH + l * 4);
        }
        #pragma unroll 4
        for (int j = 0; j < 4; ++j) {
            if (node[j] >= 0)
                *(f32x4*)(out + (long)node[j] * NCH + l * 4) = v[j];
        }
    }
    if (t == 0) gbase = atomicAdd(&cn[0], myNC);
    __syncthreads();
    const int gb = gbase;
    if (t < myNC) glist[gb + t] = ncList[t];
    // ---- edge metadata: 16 threads per non-cached node
    const int mstride = cn[1];
    for (int i = t >> 4; i < myNC; i += 16) {
        const int j = t & 15;
        const int n = ncList[i];
        const int p0 = ptr[n], p1 = ptr[n + 1];
        const int deg = p1 - p0;
        int pk = NREL << 24;                       // dead edge default
        if (j < deg) {
            const int e  = p0 + j;
            const int s  = idx[e];
            const int tt = et[e];
            const int r  = (mask_used(um, mstride, s) && tt >= 0 && tt < NREL)
                           ? tt : NREL;
            pk = s | (r << 24);
        }
        if (j == 0) {
            if (deg > 16) pk |= (1 << 29);         // overflow flag
            invdegG[gb + i] = (deg > 0) ? 1.0f / (float)deg : 0.0f;
        }
        eMeta[(size_t)(gb + i) * 16 + j] = pk;
    }
}

// ---------------------------------------------------------------------------
// K3: 16 non-cached nodes per block; ONE FULL WAVE PER NODE (4 seq).
// Metadata from eMeta (uniform 4x16B loads, no dependent chain); all 16
// row-gathers (512 B each, f32x2/lane) in flight simultaneously.
// ---------------------------------------------------------------------------
__global__ __launch_bounds__(256, 4)
void k_main(const float* __restrict__ x, const unsigned short* __restrict__ Wb,
            const int* __restrict__ ptr, const int* __restrict__ idx,
            const int* __restrict__ et, const unsigned char* __restrict__ um,
            const int* __restrict__ cn, const int* __restrict__ glist,
            const float* __restrict__ invdegG, const int* __restrict__ eMeta,
            float* __restrict__ out) {
    __shared__ __align__(16) char As[16 * NREL * NCH * 2];   // 32 KB, XOR-swizzled
    __shared__ int   nid[16];
    __shared__ float invdeg[16];

    const int cnt  = cn[0];
    const int base = blockIdx.x * 16;
    if (base >= cnt) return;
    const int mstride = cn[1];
    const int t = threadIdx.x;
    if (t < 16) {
        const int i = base + t;
        nid[t]    = (i < cnt) ? glist[i] : -1;
        invdeg[t] = (i < cnt) ? invdegG[i] : 0.0f;
    }
    __syncthreads();

    const int wv   = t >> 6;
    const int lane = t & 63;

    for (int sn = 0; sn < 4; ++sn) {
        const int nd = wv * 4 + sn;
        const int n  = nid[nd];                    // wave-uniform (LDS bcast)
        if (n < 0) continue;
        const int slot = __builtin_amdgcn_readfirstlane(base + nd);
        const int* mp  = eMeta + (size_t)slot * 16;
        const int4 m0 = *(const int4*)(mp);
        const int4 m1 = *(const int4*)(mp + 4);
        const int4 m2 = *(const int4*)(mp + 8);
        const int4 m3 = *(const int4*)(mp + 12);
        int pk[16] = {m0.x, m0.y, m0.z, m0.w, m1.x, m1.y, m1.z, m1.w,
                      m2.x, m2.y, m2.z, m2.w, m3.x, m3.y, m3.z, m3.w};
        // all 16 gathers issued before any consumption
        f32x2 xv[16];
        #pragma unroll 16
        for (int e = 0; e < 16; ++e)
            xv[e] = *(const f32x2*)(x + (long)(pk[e] & 0xFFFFFF) * NCH + lane * 2);
        float acc[NREL][2];
        #pragma unroll
        for (int q = 0; q < NREL; ++q) { acc[q][0] = 0.0f; acc[q][1] = 0.0f; }
        #pragma unroll 16
        for (int e = 0; e < 16; ++e) {
            const int r = (pk[e] >> 24) & 0xF;
            #pragma unroll
            for (int q = 0; q < NREL; ++q) {
                const float sel = (r == q) ? 1.0f : 0.0f;
                acc[q][0] += sel * xv[e][0];
                acc[q][1] += sel * xv[e][1];
            }
        }
        if (pk[0] & (1 << 29)) {                   // rare: deg > 16 fallback
            const int p0 = ptr[n], p1 = ptr[n + 1];
            for (int e = p0 + 16; e < p1; ++e) {
                const int s  = idx[e];
                const int tt = et[e];
                if (mask_used(um, mstride, s) && tt >= 0 && tt < NREL) {
                    const f32x2 w = *(const f32x2*)(x + (long)s * NCH + lane * 2);
                    #pragma unroll
                    for (int q = 0; q < NREL; ++q) {
                        const float sel = (tt == q) ? 1.0f : 0.0f;
                        acc[q][0] += sel * w[0];
                        acc[q][1] += sel * w[1];
                    }
                }
            }
        }
        // bf16 pack -> swizzled LDS A[nd][k], k = q*128 + 2*lane
        #pragma unroll
        for (int q = 0; q < NREL; ++q) {
            ushort2 pkv;
            pkv.x = f2bf(acc[q][0]);
            pkv.y = f2bf(acc[q][1]);
            const int addr = (nd * 2048 + (q * NCH + lane * 2) * 2)
                             ^ ((nd & 7) << 4);
            *(ushort2*)(As + addr) = pkv;
        }
    }
    __syncthreads();

    // MFMA: wave wv covers output cols [wv*32, wv*32+32)
    const int row  = lane & 15;
    const int koff = (lane >> 4) * 8;
    const int col0 = wv * 32 + row;
    f32x4 c0 = {0.f, 0.f, 0.f, 0.f}, c1 = {0.f, 0.f, 0.f, 0.f};
    #pragma unroll 8
    for (int kt = 0; kt < 32; ++kt) {
        const int aaddr = (row * 2048 + (kt * 32 + koff) * 2) ^ ((row & 7) << 4);
        const bf16x8 a  = *(const bf16x8*)(As + aaddr);
        const bf16x8 b0 = *(const bf16x8*)(Wb + ((kt * NCH + col0) << 5) + koff);
        const bf16x8 b1 = *(const bf16x8*)(Wb + ((kt * NCH + col0 + 16) << 5) + koff);
        c0 = __builtin_amdgcn_mfma_f32_16x16x32_bf16(a, b0, c0, 0, 0, 0);
        c1 = __builtin_amdgcn_mfma_f32_16x16x32_bf16(a, b1, c1, 0, 0, 0);
    }
    const int r4 = (lane >> 4) * 4;
    #pragma unroll
    for (int j = 0; j < 4; ++j) {
        const int rr = r4 + j;
        const int n  = nid[rr];
        if (n >= 0) {
            const float sc = invdeg[rr];
            out[(long)n * NCH + col0]      = c0[j] * sc;
            out[(long)n * NCH + col0 + 16] = c1[j] * sc;
        }
    }
}

extern "C" void kernel_launch(void* const* d_in, const int* in_sizes, int n_in,
                              void* d_out, int out_size, void* d_ws, size_t ws_size,
                              hipStream_t stream) {
    const float*         x   = (const float*)d_in[0];
    const float*         W   = (const float*)d_in[1];
    const float*         hb  = (const float*)d_in[2];
    const int*           ptr = (const int*)d_in[3];
    const int*           idx = (const int*)d_in[4];
    const int*           et  = (const int*)d_in[5];
    const unsigned char* um  = (const unsigned char*)d_in[6];
    const int*           hm  = (const int*)d_in[7];
    const int*           hs  = (const int*)d_in[8];
    float* out = (float*)d_out;

    const int num_node = in_sizes[7];           // history_map length

    // ws layout: cn | glist | invdegG | eMeta | Wb
    const size_t a256 = 255;
    size_t off = 0;
    int* cn = (int*)d_ws;                         off += 256;
    int* glist = (int*)((char*)d_ws + off);       off += (((size_t)num_node * 4) + a256) & ~a256;
    float* invdegG = (float*)((char*)d_ws + off); off += (((size_t)num_node * 4) + a256) & ~a256;
    int* eMeta = (int*)((char*)d_ws + off);       off += (((size_t)num_node * 64) + a256) & ~a256;
    unsigned short* Wb = (unsigned short*)((char*)d_ws + off);

    k_prep<<<(NREL * NCH * NCH + 255) / 256, 256, 0, stream>>>(W, Wb, cn, um);
    k_hist<<<(num_node + 31) / 32, 256, 0, stream>>>(
        hb, hm, hs, ptr, idx, et, um, out, cn, glist, invdegG, eMeta, num_node);
    k_main<<<(num_node + 15) / 16, 256, 0, stream>>>(
        x, Wb, ptr, idx, et, um, cn, glist, invdegG, eMeta, out);
}

// Round 8
// 67.811 us; speedup vs baseline: 1.8034x; 1.1345x over previous
//
#include <hip/hip_runtime.h>
#include <hip/hip_bf16.h>
#include <stdint.h>

typedef __attribute__((ext_vector_type(4))) float f32x4;
typedef __attribute__((ext_vector_type(8))) short bf16x8;

#define NCH  128
#define NREL 8

__device__ __forceinline__ unsigned short f2bf(float f) {
    unsigned u = __builtin_bit_cast(unsigned, f);
    u += 0x7fffu + ((u >> 16) & 1u);          // RNE to bf16
    return (unsigned short)(u >> 16);
}

// ---------------------------------------------------------------------------
// R8: source = R2 (67.9 us baseline) with ONE change: k_main's epilogue
// stages C through LDS and writes contiguous 512B rows (R4 measured 3.9x
// HBM write amplification from the old scattered-4B epilogue).
// ---------------------------------------------------------------------------
__global__ __launch_bounds__(256)
void k_prep(const float* __restrict__ W, unsigned short* __restrict__ Wb,
            int* __restrict__ cn, const unsigned char* __restrict__ um_raw) {
    int o = blockIdx.x * 256 + threadIdx.x;
    if (o < NREL * NCH * NCH) {
        int kk = o & 31;
        int h  = (o >> 5) & (NCH - 1);
        int kt = o >> 12;
        int k  = kt * 32 + kk;
        Wb[o] = f2bf(W[k * NCH + h]);
    }
    if (blockIdx.x == 0) {
        __shared__ unsigned sA, sB;
        const int t = threadIdx.x;
        if (t == 0) { sA = 0; sB = 0; }
        __syncthreads();
        unsigned a = 0, b = 0;
        #pragma unroll 4
        for (int p = t; p < 1024; p += 256) {
            unsigned v = um_raw[p];
            if ((p & 3) != 0) a |= v;
            if ((p & 7) == 4) b |= v;
        }
        if (a) atomicOr(&sA, 1u);
        if (b) atomicOr(&sB, 1u);
        __syncthreads();
        if (t == 0) {
            cn[0] = 0;
            cn[1] = sA ? 1 : (sB ? 4 : 8);    // mask element stride in bytes
        }
    }
}

__device__ __forceinline__ bool mask_used(const unsigned char* um, int stride, int s) {
    if (stride == 1) return um[s] != 0;
    if (stride == 4) return ((const int*)um)[s] != 0;
    return ((const long long*)um)[s] != 0;
}

__global__ __launch_bounds__(256)
void k_hist(const float* __restrict__ hb, const int* __restrict__ hm,
            const int* __restrict__ hs, float* __restrict__ out,
            int* __restrict__ cn, int* __restrict__ glist, int num_node) {
    __shared__ int ncList[32];
    __shared__ int cList[32];
    __shared__ int nNC, nC, gbase;
    const int t = threadIdx.x;
    if (t == 0) { nNC = 0; nC = 0; }
    __syncthreads();
    const int n = blockIdx.x * 32 + t;
    if (t < 32 && n < num_node) {
        const bool cached = (hs[0] > 0) && (hm[n] != -1);
        if (cached) { int p = atomicAdd(&nC, 1);  cList[p]  = n; }
        else        { int p = atomicAdd(&nNC, 1); ncList[p] = n; }
    }
    __syncthreads();
    const int hw = t >> 5, l = t & 31;
    int   node[4];
    f32x4 v[4];
    #pragma unroll 4
    for (int j = 0; j < 4; ++j) {
        const int i = hw + j * 8;
        node[j] = (i < nC) ? cList[i] : -1;
        if (node[j] >= 0)
            v[j] = *(const f32x4*)(hb + (long)node[j] * NCH + l * 4);
    }
    #pragma unroll 4
    for (int j = 0; j < 4; ++j) {
        if (node[j] >= 0)
            *(f32x4*)(out + (long)node[j] * NCH + l * 4) = v[j];
    }
    if (t == 0) gbase = atomicAdd(&cn[0], nNC);
    __syncthreads();
    if (t < nNC) glist[gbase + t] = ncList[t];
}

__global__ __launch_bounds__(256, 4)
void k_main(const float* __restrict__ x, const unsigned short* __restrict__ Wb,
            const int* __restrict__ ptr, const int* __restrict__ idx,
            const int* __restrict__ et, const unsigned char* __restrict__ um,
            const int* __restrict__ cn, const int* __restrict__ glist,
            float* __restrict__ out) {
    __shared__ __align__(16) char As[16 * NREL * NCH * 2];   // 32 KB, XOR-swizzled
    __shared__ int   nid[16];
    __shared__ float invdeg[16];

    const int cnt  = cn[0];
    const int base = blockIdx.x * 16;
    if (base >= cnt) return;
    const int mstride = cn[1];
    const int t = threadIdx.x;
    if (t < 16) {
        const int e = base + t;
        nid[t]    = (e < cnt) ? glist[e] : -1;
        invdeg[t] = 0.0f;
    }
    __syncthreads();

    const int hw = t >> 5;          // half-wave id 0..7
    const int l  = t & 31;          // lane in half-wave; owns channels 4l..4l+3
    const int lbase = t & 32;       // wave-lane base of this half-wave

    for (int rep = 0; rep < 2; ++rep) {
        const int nd = hw + rep * 8;
        const int n  = nid[nd];
        float acc[NREL][4];
        #pragma unroll
        for (int r = 0; r < NREL; ++r)
            #pragma unroll
            for (int j = 0; j < 4; ++j) acc[r][j] = 0.0f;
        if (n >= 0) {
            const int p0 = ptr[n], p1 = ptr[n + 1];
            const int deg = p1 - p0;
            if (l == 0) invdeg[nd] = (deg > 0) ? 1.0f / (float)deg : 0.0f;
            int myS = 0, myR = NREL;
            if (l < 16 && (p0 + l) < p1) {
                const int e = p0 + l;
                myS = idx[e];
                const int tt = et[e];
                myR = (mask_used(um, mstride, myS) && tt >= 0 && tt < NREL) ? tt : NREL;
            }
            #pragma unroll 2
            for (int ch = 0; ch < 2; ++ch) {
                int   rr8[8], ss8[8];
                f32x4 xv[8];
                #pragma unroll 8
                for (int e = 0; e < 8; ++e) {
                    rr8[e] = __shfl(myR, lbase + ch * 8 + e, 64);
                    ss8[e] = __shfl(myS, lbase + ch * 8 + e, 64);
                    xv[e]  = *(const f32x4*)(x + (long)ss8[e] * NCH + l * 4);
                }
                #pragma unroll 8
                for (int e = 0; e < 8; ++e) {
                    const int r = rr8[e];
                    #pragma unroll
                    for (int q = 0; q < NREL; ++q) {
                        const float sel = (r == q) ? 1.0f : 0.0f;
                        acc[q][0] += sel * xv[e].x;
                        acc[q][1] += sel * xv[e].y;
                        acc[q][2] += sel * xv[e].z;
                        acc[q][3] += sel * xv[e].w;
                    }
                }
            }
            for (int e = p0 + 16; e < p1; ++e) {   // general fallback (deg > 16)
                const int s = idx[e];
                const int tt = et[e];
                if (mask_used(um, mstride, s) && tt >= 0 && tt < NREL) {
                    const f32x4 w = *(const f32x4*)(x + (long)s * NCH + l * 4);
                    #pragma unroll
                    for (int q = 0; q < NREL; ++q) {
                        const float sel = (tt == q) ? 1.0f : 0.0f;
                        acc[q][0] += sel * w.x;
                        acc[q][1] += sel * w.y;
                        acc[q][2] += sel * w.z;
                        acc[q][3] += sel * w.w;
                    }
                }
            }
        }
        #pragma unroll
        for (int q = 0; q < NREL; ++q) {
            ushort4 pkv;
            pkv.x = f2bf(acc[q][0]); pkv.y = f2bf(acc[q][1]);
            pkv.z = f2bf(acc[q][2]); pkv.w = f2bf(acc[q][3]);
            const int eb   = (q * NCH + l * 4) * 2;
            const int addr = (nd * 2048 + eb) ^ ((nd & 7) << 4);
            *(ushort4*)(As + addr) = pkv;
        }
    }
    __syncthreads();

    const int wv   = t >> 6;
    const int lane = t & 63;
    const int row  = lane & 15;
    const int koff = (lane >> 4) * 8;
    const int col0 = wv * 32 + row;
    f32x4 c0 = {0.f, 0.f, 0.f, 0.f}, c1 = {0.f, 0.f, 0.f, 0.f};
    #pragma unroll 8
    for (int kt = 0; kt < 32; ++kt) {
        const int aaddr = (row * 2048 + (kt * 32 + koff) * 2) ^ ((row & 7) << 4);
        const bf16x8 a  = *(const bf16x8*)(As + aaddr);
        const bf16x8 b0 = *(const bf16x8*)(Wb + ((kt * NCH + col0) << 5) + koff);
        const bf16x8 b1 = *(const bf16x8*)(Wb + ((kt * NCH + col0 + 16) << 5) + koff);
        c0 = __builtin_amdgcn_mfma_f32_16x16x32_bf16(a, b0, c0, 0, 0, 0);
        c1 = __builtin_amdgcn_mfma_f32_16x16x32_bf16(a, b1, c1, 0, 0, 0);
    }

    // ---- NEW epilogue: stage scaled C in LDS, store contiguous 512B rows ----
    __syncthreads();                       // all MFMA reads of As complete
    float* Cs = (float*)As;                // reuse As as float Cs[16][128]
    {
        const int r4 = (lane >> 4) * 4;
        #pragma unroll
        for (int j = 0; j < 4; ++j) {
            const int rr = r4 + j;
            const float sc = invdeg[rr];
            Cs[rr * NCH + col0]      = c0[j] * sc;
            Cs[rr * NCH + col0 + 16] = c1[j] * sc;
        }
    }
    __syncthreads();
    #pragma unroll 2
    for (int rp = 0; rp < 2; ++rp) {
        const int rr = hw + rp * 8;
        const int n  = nid[rr];
        if (n >= 0) {
            const f32x4 v = *(const f32x4*)(Cs + rr * NCH + l * 4);
            *(f32x4*)(out + (long)n * NCH + l * 4) = v;
        }
    }
}

extern "C" void kernel_launch(void* const* d_in, const int* in_sizes, int n_in,
                              void* d_out, int out_size, void* d_ws, size_t ws_size,
                              hipStream_t stream) {
    const float*         x   = (const float*)d_in[0];
    const float*         W   = (const float*)d_in[1];
    const float*         hb  = (const float*)d_in[2];
    const int*           ptr = (const int*)d_in[3];
    const int*           idx = (const int*)d_in[4];
    const int*           et  = (const int*)d_in[5];
    const unsigned char* um  = (const unsigned char*)d_in[6];
    const int*           hm  = (const int*)d_in[7];
    const int*           hs  = (const int*)d_in[8];
    float* out = (float*)d_out;

    const int num_node = in_sizes[7];           // history_map length

    int* cn    = (int*)d_ws;
    int* glist = (int*)((char*)d_ws + 256);
    size_t wb_off = 256 + (((size_t)num_node * 4 + 255) / 256) * 256;
    unsigned short* Wb = (unsigned short*)((char*)d_ws + wb_off);

    k_prep<<<(NREL * NCH * NCH + 255) / 256, 256, 0, stream>>>(W, Wb, cn, um);
    k_hist<<<(num_node + 31) / 32, 256, 0, stream>>>(hb, hm, hs, out, cn, glist, num_node);
    k_main<<<(num_node + 15) / 16, 256, 0, stream>>>(x, Wb, ptr, idx, et, um, cn, glist, out);
}